// Round 7
// baseline (206.026 us; speedup 1.0000x reference)
//
#include <hip/hip_runtime.h>
#include <hip/hip_bf16.h>

// ---------------------------------------------------------------------------
// AttentionBlockWithSelfAttention on MI355X (gfx950)
// B=4, Cin=128, Fi=64, H=W=64, N=4096, d_qk=8
//
// THREE dispatches. Harness floor identified (r6): ~50us of 0xAA ws-poison
// fill inside the timed region; controllable budget is the 3 kernels.
//   k1 conv_fused: BN folded per-lane; c=relu(conv), Q(x log2e)/K/V bf16
//   k2 attn_part:  flash attention, KV split x8, swapped-operand softmax,
//                  BARRIER-FREE inner loop: K/V fragments loaded directly
//                  from global (L2-resident, massive reuse); P via per-wave
//                  LDS only. exp2 domain + T13 defer-max.
//   k3 combine:    merge 8 partials (exp2 weights) + psi/sigmoid + x*psi
// ---------------------------------------------------------------------------

typedef short bf16x8 __attribute__((ext_vector_type(8)));
typedef unsigned short u16x8 __attribute__((ext_vector_type(8)));
typedef unsigned short u16x4 __attribute__((ext_vector_type(4)));
typedef float f32x4 __attribute__((ext_vector_type(4)));

__device__ __forceinline__ unsigned short f2b16(float f) {
  return __builtin_bit_cast(unsigned short, __float2bfloat16(f));
}
__device__ __forceinline__ float b2f(unsigned short u) {
  return __bfloat162float(__builtin_bit_cast(__hip_bfloat16, u));
}

#define EPSV 1e-5f
#define LOG2E 1.44269504088896340736f

// ---- workspace layout (bytes) ----
#define C_OFF      0u                      // 4*64*4096 bf16 = 2097152
#define Q_OFF      (C_OFF + 2097152u)      // 4*4096*8 bf16 = 262144
#define K_OFF      (Q_OFF + 262144u)
#define V_OFF      (K_OFF + 262144u)       // 4*64*4096 bf16 = 2097152
#define OPART_OFF  (V_OFF + 2097152u)      // 32*4096*64 bf16 = 16777216
#define ML_OFF     (OPART_OFF + 16777216u) // 32*4096*2 f32 = 1048576

// ===========================================================================
// conv_fused: one block per (b, 32-point tile). 512 blocks, 4 waves.
// BN folding done per-lane in registers.
__global__ __launch_bounds__(256) void conv_fused_kernel(
    const float* __restrict__ g, const float* __restrict__ x,
    const float* __restrict__ wg_w, const float* __restrict__ wg_b,
    const float* __restrict__ bng_w, const float* __restrict__ bng_b,
    const float* __restrict__ bng_m, const float* __restrict__ bng_v,
    const float* __restrict__ wx_w, const float* __restrict__ wx_b,
    const float* __restrict__ bnx_w, const float* __restrict__ bnx_b,
    const float* __restrict__ bnx_m, const float* __restrict__ bnx_v,
    const float* __restrict__ q_w, const float* __restrict__ q_b,
    const float* __restrict__ k_w, const float* __restrict__ k_b,
    const float* __restrict__ v_w, const float* __restrict__ v_b,
    unsigned short* __restrict__ cb, unsigned short* __restrict__ Qb,
    unsigned short* __restrict__ Kb, unsigned short* __restrict__ Vb)
{
  __shared__ __attribute__((aligned(16))) unsigned short xt[32][264];    // [n][k]
  __shared__ __attribute__((aligned(16))) unsigned short clds[32][72];   // [n][o]
  __shared__ __attribute__((aligned(16))) unsigned short vstage[64][36]; // [ch][n]

  const int t = threadIdx.x;
  const int bid = blockIdx.x;
  const int b = bid >> 7;
  const int n0 = (bid & 127) << 5;

  // ---- stage [g;x] tile transposed to [n][k] bf16 ----
  {
    const int col4 = t & 7;          // n offset = col4*4
    const int rowg = t >> 3;         // rows rowg*8 .. +7
    float4 v[8];
    #pragma unroll
    for (int rr = 0; rr < 8; ++rr) {
      int row = rowg * 8 + rr;
      const float* src = (row < 128)
          ? (g + ((size_t)(b * 128 + row)) * 4096 + n0 + col4 * 4)
          : (x + ((size_t)(b * 128 + (row - 128))) * 4096 + n0 + col4 * 4);
      v[rr] = *(const float4*)src;
    }
    #pragma unroll
    for (int j = 0; j < 4; ++j) {
      u16x8 pk;
      #pragma unroll
      for (int rr = 0; rr < 8; ++rr)
        pk[rr] = f2b16(((const float*)&v[rr])[j]);
      *(u16x8*)(&xt[col4 * 4 + j][rowg * 8]) = pk;
    }
  }

  const int l = t & 63, w = t >> 6;
  const int l15 = l & 15, lg = l >> 4;
  f32x4 zf = {0.f, 0.f, 0.f, 0.f};

  // ---- per-lane BN-folded A-fragments ----
  const int orow = w * 16 + l15;
  const float invg = bng_w[orow] * rsqrtf(bng_v[orow] + EPSV);
  const float invx = bnx_w[orow] * rsqrtf(bnx_v[orow] + EPSV);
  bf16x8 afrag[8];
  #pragma unroll
  for (int ks = 0; ks < 8; ++ks) {
    int k = ks * 32 + lg * 8;        // 8-chunk never straddles k=128
    const float* wp;
    float sc;
    if (k < 128) { wp = wg_w + orow * 128 + k;         sc = invg; }
    else         { wp = wx_w + orow * 128 + (k - 128); sc = invx; }
    float4 w0 = *(const float4*)wp;
    float4 w1 = *(const float4*)(wp + 4);
    u16x8 pk;
    pk[0] = f2b16(w0.x * sc); pk[1] = f2b16(w0.y * sc);
    pk[2] = f2b16(w0.z * sc); pk[3] = f2b16(w0.w * sc);
    pk[4] = f2b16(w1.x * sc); pk[5] = f2b16(w1.y * sc);
    pk[6] = f2b16(w1.z * sc); pk[7] = f2b16(w1.w * sc);
    afrag[ks] = __builtin_bit_cast(bf16x8, pk);
  }
  __syncthreads();

  // ---- conv MFMA: wave w owns o-rows [16w,16w+16), 2 n-subtiles ----
  f32x4 acc[2];
  acc[0] = acc[1] = zf;
  #pragma unroll
  for (int ks = 0; ks < 8; ++ks) {
    #pragma unroll
    for (int ns = 0; ns < 2; ++ns) {
      bf16x8 bfv = *(const bf16x8*)(&xt[ns * 16 + l15][ks * 32 + lg * 8]);
      acc[ns] = __builtin_amdgcn_mfma_f32_16x16x32_bf16(afrag[ks], bfv, acc[ns], 0, 0, 0);
    }
  }
  #pragma unroll
  for (int r = 0; r < 4; ++r) {
    int o = w * 16 + lg * 4 + r;
    float ig = bng_w[o] * rsqrtf(bng_v[o] + EPSV);
    float ix = bnx_w[o] * rsqrtf(bnx_v[o] + EPSV);
    float bc = (wg_b[o] - bng_m[o]) * ig + bng_b[o]
             + (wx_b[o] - bnx_m[o]) * ix + bnx_b[o];
    #pragma unroll
    for (int ns = 0; ns < 2; ++ns) {
      float cv = fmaxf(acc[ns][r] + bc, 0.f);
      unsigned short cv16 = f2b16(cv);
      cb[((size_t)(b * 64 + o)) * 4096 + n0 + ns * 16 + l15] = cv16;
      clds[ns * 16 + l15][o] = cv16;
    }
  }
  __syncthreads();

  // ---- QKV: 10 tiles (5 row-tiles x 2 n-subtiles) over 4 waves ----
  #pragma unroll
  for (int i = 0; i < 3; ++i) {
    int tau = w + 4 * i;
    if (tau >= 10) break;
    int t5 = tau % 5, ns = tau / 5;
    int wrow = t5 * 16 + l15;
    f32x4 a2 = zf;
    #pragma unroll
    for (int kk = 0; kk < 2; ++kk) {
      int k = kk * 32 + lg * 8;
      const float* wp = (wrow < 8)  ? (q_w + wrow * 64 + k)
                      : (wrow < 16) ? (k_w + (wrow - 8) * 64 + k)
                                    : (v_w + (wrow - 16) * 64 + k);
      float4 w0 = *(const float4*)wp;
      float4 w1 = *(const float4*)(wp + 4);
      u16x8 pk;
      pk[0] = f2b16(w0.x); pk[1] = f2b16(w0.y);
      pk[2] = f2b16(w0.z); pk[3] = f2b16(w0.w);
      pk[4] = f2b16(w1.x); pk[5] = f2b16(w1.y);
      pk[6] = f2b16(w1.z); pk[7] = f2b16(w1.w);
      bf16x8 bfv = *(const bf16x8*)(&clds[ns * 16 + l15][k]);
      a2 = __builtin_amdgcn_mfma_f32_16x16x32_bf16(
          __builtin_bit_cast(bf16x8, pk), bfv, a2, 0, 0, 0);
    }
    int ngl = n0 + ns * 16 + l15;
    if (t5 == 0) {
      u16x4 pk;
      #pragma unroll
      for (int r = 0; r < 4; ++r) {
        int row = lg * 4 + r;
        float val;
        if (row < 8) val = (a2[r] + q_b[row]) * LOG2E;   // exp2-domain Q
        else         val = a2[r] + k_b[row - 8];
        pk[r] = f2b16(val);
      }
      if (lg < 2)
        *(u16x4*)(Qb + (((size_t)b << 12) + ngl) * 8 + lg * 4) = pk;
      else
        *(u16x4*)(Kb + (((size_t)b << 12) + ngl) * 8 + (lg - 2) * 4) = pk;
    } else {
      #pragma unroll
      for (int r = 0; r < 4; ++r) {
        int vch = (t5 - 1) * 16 + lg * 4 + r;
        vstage[vch][ns * 16 + l15] = f2b16(a2[r] + v_b[vch]);
      }
    }
  }
  __syncthreads();

  // ---- coalesced V store: 64ch x 32n ----
  #pragma unroll
  for (int i = 0; i < 2; ++i) {
    int idx = t + 256 * i;           // 0..511
    int row = idx >> 3, seg = idx & 7;
    u16x4 pv = *(const u16x4*)(&vstage[row][seg * 4]);
    *(u16x4*)(Vb + ((size_t)(b * 64 + row)) * 4096 + n0 + seg * 4) = pv;
  }
}

// ===========================================================================
// attn_partial: flash attention, KV chunk of 512. 2048 blocks. BARRIER-FREE:
// K/V fragments loaded directly from global (L2-resident); P via per-wave LDS.
__global__ __launch_bounds__(256) void attn_partial_kernel(
    const unsigned short* __restrict__ Qb, const unsigned short* __restrict__ Kb,
    const unsigned short* __restrict__ Vb,
    unsigned short* __restrict__ Opart, float* __restrict__ ml)
{
  // P in B-fragment layout: [wave][kk][q=l15][idx]; row stride 40 elems = 80B
  __shared__ __attribute__((aligned(16))) unsigned short plds[4][2][16][40];

  const int t = threadIdx.x;
  const int bid = blockIdx.x;
  const int qt = bid & 63;
  const int b = (bid >> 6) & 3;
  const int ci = bid >> 8;            // KV chunk 0..7 (512 each)
  const int n0 = qt << 6;
  const int l = t & 63, w = t >> 6;
  const int l15 = l & 15, lg = l >> 4;

  bf16x8 qf = {0, 0, 0, 0, 0, 0, 0, 0};
  if (lg == 0)
    qf = *(const bf16x8*)(Qb + (((size_t)b << 12) + n0 + w * 16 + l15) * 8);

  f32x4 zf = {0.f, 0.f, 0.f, 0.f};
  f32x4 O[4];                         // O^T: lane ch=ct*16+lg*4+r, q=l15
  O[0] = O[1] = O[2] = O[3] = zf;
  float m_run = -INFINITY;            // per-lane scalars (q = l15)
  float l_run = 0.f;

  const unsigned short* Kb_b = Kb + (((size_t)b << 12) + l15) * 8;
  const unsigned short* Vb_b = Vb + ((size_t)(b * 64 + l15)) * 4096 + lg * 8;

  const int m_lo = ci << 9, m_hi = (ci + 1) << 9;
  for (int m0 = m_lo; m0 < m_hi; m0 += 64) {
    // ---- energy (swapped): e[mt][r] = E[kv=mt*16+lg*4+r][q=l15] ----
    f32x4 e[4];
    #pragma unroll
    for (int mt = 0; mt < 4; ++mt) {
      bf16x8 kf = *(const bf16x8*)(Kb_b + (size_t)(m0 + mt * 16) * 8);
      e[mt] = __builtin_amdgcn_mfma_f32_16x16x32_bf16(kf, qf, zf, 0, 0, 0);
    }

    // ---- in-register softmax for q = l15 ----
    float vm = fmaxf(fmaxf(fmaxf(e[0][0], e[0][1]), fmaxf(e[0][2], e[0][3])),
                     fmaxf(fmaxf(e[1][0], e[1][1]), fmaxf(e[1][2], e[1][3])));
    float vm2 = fmaxf(fmaxf(fmaxf(e[2][0], e[2][1]), fmaxf(e[2][2], e[2][3])),
                      fmaxf(fmaxf(e[3][0], e[3][1]), fmaxf(e[3][2], e[3][3])));
    vm = fmaxf(vm, vm2);
    vm = fmaxf(vm, __shfl_xor(vm, 16));
    vm = fmaxf(vm, __shfl_xor(vm, 32));

    bool nosk = __any(vm > m_run + 8.f);   // T13: rescale only on real growth
    float nm = nosk ? fmaxf(m_run, vm) : m_run;
    float s = 0.f;
    #pragma unroll
    for (int mt = 0; mt < 4; ++mt) {
      #pragma unroll
      for (int r = 0; r < 4; ++r) {
        float p = __builtin_amdgcn_exp2f(e[mt][r] - nm);
        e[mt][r] = p;
        s += p;
      }
    }
    s += __shfl_xor(s, 16);
    s += __shfl_xor(s, 32);
    if (nosk) {
      float sc = __builtin_amdgcn_exp2f(m_run - nm);
      l_run = l_run * sc + s;
      m_run = nm;
      #pragma unroll
      for (int ct = 0; ct < 4; ++ct)
        #pragma unroll
        for (int r = 0; r < 4; ++r) O[ct][r] *= sc;
    } else {
      l_run += s;
    }

    // ---- write P in B-fragment layout (4x ds_write_b64, per-wave buffer) ----
    #pragma unroll
    for (int mt = 0; mt < 4; ++mt) {
      u16x4 pk;
      #pragma unroll
      for (int r = 0; r < 4; ++r) pk[r] = f2b16(e[mt][r]);
      int kk = mt >> 1;
      int lgr = 2 * (mt & 1) + (lg >> 1);
      int j0 = 4 * (lg & 1);
      *(u16x4*)(&plds[w][kk][l15][lgr * 8 + j0]) = pk;
    }
    // same-wave RAW on plds: in-order DS per wave + compiler lgkmcnt

    // ---- PV (swapped): O^T[ct] += V[ch][kv] . P[kv][q], V direct from L2 ----
    #pragma unroll
    for (int ct = 0; ct < 4; ++ct) {
      #pragma unroll
      for (int kk = 0; kk < 2; ++kk) {
        bf16x8 vf = *(const bf16x8*)(Vb_b + (size_t)ct * 16 * 4096 + m0 + kk * 32);
        bf16x8 pfr = *(const bf16x8*)(&plds[w][kk][l15][lg * 8]);
        O[ct] = __builtin_amdgcn_mfma_f32_16x16x32_bf16(vf, pfr, O[ct], 0, 0, 0);
      }
    }
    // NO barrier: waves fully independent
  }

  // ---- store partials: O^T bf16 + (m,l) f32 ----
  const size_t pb = ((size_t)(ci * 4 + b)) << 12;
  const int qg = n0 + w * 16 + l15;
  #pragma unroll
  for (int ct = 0; ct < 4; ++ct) {
    u16x4 pk;
    #pragma unroll
    for (int r = 0; r < 4; ++r) pk[r] = f2b16(O[ct][r]);
    *(u16x4*)(Opart + (pb + qg) * 64 + ct * 16 + lg * 4) = pk;
  }
  if (lg == 0) {
    float2 mv;
    mv.x = m_run; mv.y = l_run;
    *(float2*)(ml + (pb + qg) * 2) = mv;
  }
}

// ===========================================================================
// combine: merge 8 KV-chunk partials + fused epilogue. 1024 blocks, 16 q each.
__global__ __launch_bounds__(256) void combine_kernel(
    const unsigned short* __restrict__ Opart, const float* __restrict__ ml,
    const unsigned short* __restrict__ cb, const float* __restrict__ xin,
    const float* __restrict__ psi_w, const float* __restrict__ psi_b,
    const float* __restrict__ bnp_w, const float* __restrict__ bnp_b,
    const float* __restrict__ bnp_m, const float* __restrict__ bnp_v,
    const float* __restrict__ sa_gamma,
    float* __restrict__ out)
{
  __shared__ __attribute__((aligned(16))) unsigned short c_lds[64][20];
  __shared__ __attribute__((aligned(8))) float2 ml_lds[16][8];
  __shared__ float psi_lds[16];

  const int t = threadIdx.x;
  const int bid = blockIdx.x;
  const int b = bid >> 8;
  const int n0 = (bid & 255) << 4;

  {
    int row = t >> 2, seg = t & 3;
    *(u16x4*)(&c_lds[row][seg * 4]) =
        *(const u16x4*)(cb + ((size_t)(b * 64 + row)) * 4096 + n0 + seg * 4);
  }
  if (t < 128) {
    int q = t >> 3, ci = t & 7;
    ml_lds[q][ci] = *(const float2*)(ml + ((((size_t)(ci * 4 + b)) << 12) + n0 + q) * 2);
  }
  __syncthreads();

  const float invp = bnp_w[0] * rsqrtf(bnp_v[0] + EPSV);
  const float psi_c = (psi_b[0] - bnp_m[0]) * invp + bnp_b[0];
  const float gamma = sa_gamma[0];

  const int q = t >> 4, cg = t & 15;
  const int qg = n0 + q;

  float M = -INFINITY;
  #pragma unroll
  for (int ci = 0; ci < 8; ++ci) M = fmaxf(M, ml_lds[q][ci].x);
  float L = 0.f, wgt[8];
  #pragma unroll
  for (int ci = 0; ci < 8; ++ci) {
    wgt[ci] = __builtin_amdgcn_exp2f(ml_lds[q][ci].x - M);
    L += wgt[ci] * ml_lds[q][ci].y;
  }
  float o4[4] = {0.f, 0.f, 0.f, 0.f};
  #pragma unroll
  for (int ci = 0; ci < 8; ++ci) {
    u16x4 p = *(const u16x4*)(Opart + ((((size_t)(ci * 4 + b)) << 12) + qg) * 64 + cg * 4);
    float wv = wgt[ci];
    #pragma unroll
    for (int k = 0; k < 4; ++k) o4[k] += wv * b2f(p[k]);
  }
  const float invL = 1.f / L;
  float ps = 0.f;
  #pragma unroll
  for (int k = 0; k < 4; ++k) {
    int ch = cg * 4 + k;
    ps += (psi_w[ch] * invp) * (gamma * (o4[k] * invL) + b2f(c_lds[ch][q]));
  }
  ps += __shfl_xor(ps, 1);
  ps += __shfl_xor(ps, 2);
  ps += __shfl_xor(ps, 4);
  ps += __shfl_xor(ps, 8);
  if (cg == 0)
    psi_lds[q] = 1.f / (1.f + __expf(-(ps + psi_c)));
  __syncthreads();

  #pragma unroll
  for (int i = 0; i < 2; ++i) {
    int idx = t + 256 * i;
    int f = idx >> 2, c4 = idx & 3;
    size_t off = ((size_t)(b * 128 + f)) * 4096 + n0 + c4 * 4;
    float4 xv = *(const float4*)(xin + off);
    float4 ov;
    ov.x = xv.x * psi_lds[c4 * 4 + 0];
    ov.y = xv.y * psi_lds[c4 * 4 + 1];
    ov.z = xv.z * psi_lds[c4 * 4 + 2];
    ov.w = xv.w * psi_lds[c4 * 4 + 3];
    *(float4*)(out + off) = ov;
  }
}

// ===========================================================================
extern "C" void kernel_launch(void* const* d_in, const int* in_sizes, int n_in,
                              void* d_out, int out_size, void* d_ws, size_t ws_size,
                              hipStream_t stream) {
  (void)in_sizes; (void)n_in; (void)out_size; (void)ws_size;
  const float* g     = (const float*)d_in[0];
  const float* x     = (const float*)d_in[1];
  const float* wg_w  = (const float*)d_in[2];
  const float* wg_b  = (const float*)d_in[3];
  const float* bng_w = (const float*)d_in[4];
  const float* bng_b = (const float*)d_in[5];
  const float* bng_m = (const float*)d_in[6];
  const float* bng_v = (const float*)d_in[7];
  const float* wx_w  = (const float*)d_in[8];
  const float* wx_b  = (const float*)d_in[9];
  const float* bnx_w = (const float*)d_in[10];
  const float* bnx_b = (const float*)d_in[11];
  const float* bnx_m = (const float*)d_in[12];
  const float* bnx_v = (const float*)d_in[13];
  const float* q_w   = (const float*)d_in[14];
  const float* q_b   = (const float*)d_in[15];
  const float* k_w   = (const float*)d_in[16];
  const float* k_b   = (const float*)d_in[17];
  const float* v_w   = (const float*)d_in[18];
  const float* v_b   = (const float*)d_in[19];
  const float* sa_g  = (const float*)d_in[20];
  const float* psi_w = (const float*)d_in[21];
  const float* psi_b = (const float*)d_in[22];
  const float* bnp_w = (const float*)d_in[23];
  const float* bnp_b = (const float*)d_in[24];
  const float* bnp_m = (const float*)d_in[25];
  const float* bnp_v = (const float*)d_in[26];
  float* out = (float*)d_out;

  char* ws = (char*)d_ws;
  unsigned short* cb = (unsigned short*)(ws + C_OFF);
  unsigned short* Qb = (unsigned short*)(ws + Q_OFF);
  unsigned short* Kb = (unsigned short*)(ws + K_OFF);
  unsigned short* Vb = (unsigned short*)(ws + V_OFF);
  unsigned short* Opart = (unsigned short*)(ws + OPART_OFF);
  float* mlb = (float*)(ws + ML_OFF);

  hipLaunchKernelGGL(conv_fused_kernel, dim3(512), dim3(256), 0, stream,
                     g, x, wg_w, wg_b, bng_w, bng_b, bng_m, bng_v,
                     wx_w, wx_b, bnx_w, bnx_b, bnx_m, bnx_v,
                     q_w, q_b, k_w, k_b, v_w, v_b,
                     cb, Qb, Kb, Vb);

  hipLaunchKernelGGL(attn_partial_kernel, dim3(2048), dim3(256), 0, stream,
                     Qb, Kb, Vb, Opart, mlb);

  hipLaunchKernelGGL(combine_kernel, dim3(1024), dim3(256), 0, stream,
                     Opart, mlb, cb, x,
                     psi_w, psi_b, bnp_w, bnp_b, bnp_m, bnp_v, sa_g,
                     out);
}

// Round 9
// 160.435 us; speedup vs baseline: 1.2842x; 1.2842x over previous
//
#include <hip/hip_runtime.h>
#include <hip/hip_bf16.h>

// ---------------------------------------------------------------------------
// AttentionBlockWithSelfAttention on MI355X (gfx950)
// B=4, Cin=128, Fi=64, H=W=64, N=4096, d_qk=8
//
// THREE dispatches. r7 lesson: direct-from-L2 MFMA operands = latency-bound
// (VALUBusy halved); LDS staging is mandatory for operands re-read per tile.
//   k1 conv_fused: BN folded per-lane; c=relu(conv), Q(x log2e)/K/V bf16
//   k2 attn_part:  flash attention, KV split x8, swapped-operand softmax,
//                  staged K/V with T14 2-phase prefetch (regs->LDS write-late)
//   k3 combine:    merge 8 partials (exp2 weights) + psi/sigmoid + x*psi
// (r8 bench never ran: GPU acquisition timeout. Resubmitting unchanged.)
// ---------------------------------------------------------------------------

typedef short bf16x8 __attribute__((ext_vector_type(8)));
typedef unsigned short u16x8 __attribute__((ext_vector_type(8)));
typedef unsigned short u16x4 __attribute__((ext_vector_type(4)));
typedef float f32x4 __attribute__((ext_vector_type(4)));

__device__ __forceinline__ unsigned short f2b16(float f) {
  return __builtin_bit_cast(unsigned short, __float2bfloat16(f));
}
__device__ __forceinline__ float b2f(unsigned short u) {
  return __bfloat162float(__builtin_bit_cast(__hip_bfloat16, u));
}

#define EPSV 1e-5f
#define LOG2E 1.44269504088896340736f

// ---- workspace layout (bytes) ----
#define C_OFF      0u                      // 4*64*4096 bf16 = 2097152
#define Q_OFF      (C_OFF + 2097152u)      // 4*4096*8 bf16 = 262144
#define K_OFF      (Q_OFF + 262144u)
#define V_OFF      (K_OFF + 262144u)       // 4*64*4096 bf16 = 2097152
#define OPART_OFF  (V_OFF + 2097152u)      // 32*4096*64 bf16 = 16777216
#define ML_OFF     (OPART_OFF + 16777216u) // 32*4096*2 f32 = 1048576

// ===========================================================================
// conv_fused: one block per (b, 32-point tile). 512 blocks, 4 waves.
__global__ __launch_bounds__(256) void conv_fused_kernel(
    const float* __restrict__ g, const float* __restrict__ x,
    const float* __restrict__ wg_w, const float* __restrict__ wg_b,
    const float* __restrict__ bng_w, const float* __restrict__ bng_b,
    const float* __restrict__ bng_m, const float* __restrict__ bng_v,
    const float* __restrict__ wx_w, const float* __restrict__ wx_b,
    const float* __restrict__ bnx_w, const float* __restrict__ bnx_b,
    const float* __restrict__ bnx_m, const float* __restrict__ bnx_v,
    const float* __restrict__ q_w, const float* __restrict__ q_b,
    const float* __restrict__ k_w, const float* __restrict__ k_b,
    const float* __restrict__ v_w, const float* __restrict__ v_b,
    unsigned short* __restrict__ cb, unsigned short* __restrict__ Qb,
    unsigned short* __restrict__ Kb, unsigned short* __restrict__ Vb)
{
  __shared__ __attribute__((aligned(16))) unsigned short xt[32][264];    // [n][k]
  __shared__ __attribute__((aligned(16))) unsigned short clds[32][72];   // [n][o]
  __shared__ __attribute__((aligned(16))) unsigned short vstage[64][36]; // [ch][n]

  const int t = threadIdx.x;
  const int bid = blockIdx.x;
  const int b = bid >> 7;
  const int n0 = (bid & 127) << 5;

  // ---- stage [g;x] tile transposed to [n][k] bf16 ----
  {
    const int col4 = t & 7;          // n offset = col4*4
    const int rowg = t >> 3;         // rows rowg*8 .. +7
    float4 v[8];
    #pragma unroll
    for (int rr = 0; rr < 8; ++rr) {
      int row = rowg * 8 + rr;
      const float* src = (row < 128)
          ? (g + ((size_t)(b * 128 + row)) * 4096 + n0 + col4 * 4)
          : (x + ((size_t)(b * 128 + (row - 128))) * 4096 + n0 + col4 * 4);
      v[rr] = *(const float4*)src;
    }
    #pragma unroll
    for (int j = 0; j < 4; ++j) {
      u16x8 pk;
      #pragma unroll
      for (int rr = 0; rr < 8; ++rr)
        pk[rr] = f2b16(((const float*)&v[rr])[j]);
      *(u16x8*)(&xt[col4 * 4 + j][rowg * 8]) = pk;
    }
  }

  const int l = t & 63, w = t >> 6;
  const int l15 = l & 15, lg = l >> 4;
  f32x4 zf = {0.f, 0.f, 0.f, 0.f};

  // ---- per-lane BN-folded A-fragments ----
  const int orow = w * 16 + l15;
  const float invg = bng_w[orow] * rsqrtf(bng_v[orow] + EPSV);
  const float invx = bnx_w[orow] * rsqrtf(bnx_v[orow] + EPSV);
  bf16x8 afrag[8];
  #pragma unroll
  for (int ks = 0; ks < 8; ++ks) {
    int k = ks * 32 + lg * 8;        // 8-chunk never straddles k=128
    const float* wp;
    float sc;
    if (k < 128) { wp = wg_w + orow * 128 + k;         sc = invg; }
    else         { wp = wx_w + orow * 128 + (k - 128); sc = invx; }
    float4 w0 = *(const float4*)wp;
    float4 w1 = *(const float4*)(wp + 4);
    u16x8 pk;
    pk[0] = f2b16(w0.x * sc); pk[1] = f2b16(w0.y * sc);
    pk[2] = f2b16(w0.z * sc); pk[3] = f2b16(w0.w * sc);
    pk[4] = f2b16(w1.x * sc); pk[5] = f2b16(w1.y * sc);
    pk[6] = f2b16(w1.z * sc); pk[7] = f2b16(w1.w * sc);
    afrag[ks] = __builtin_bit_cast(bf16x8, pk);
  }
  __syncthreads();

  // ---- conv MFMA: wave w owns o-rows [16w,16w+16), 2 n-subtiles ----
  f32x4 acc[2];
  acc[0] = acc[1] = zf;
  #pragma unroll
  for (int ks = 0; ks < 8; ++ks) {
    #pragma unroll
    for (int ns = 0; ns < 2; ++ns) {
      bf16x8 bfv = *(const bf16x8*)(&xt[ns * 16 + l15][ks * 32 + lg * 8]);
      acc[ns] = __builtin_amdgcn_mfma_f32_16x16x32_bf16(afrag[ks], bfv, acc[ns], 0, 0, 0);
    }
  }
  #pragma unroll
  for (int r = 0; r < 4; ++r) {
    int o = w * 16 + lg * 4 + r;
    float ig = bng_w[o] * rsqrtf(bng_v[o] + EPSV);
    float ix = bnx_w[o] * rsqrtf(bnx_v[o] + EPSV);
    float bc = (wg_b[o] - bng_m[o]) * ig + bng_b[o]
             + (wx_b[o] - bnx_m[o]) * ix + bnx_b[o];
    #pragma unroll
    for (int ns = 0; ns < 2; ++ns) {
      float cv = fmaxf(acc[ns][r] + bc, 0.f);
      unsigned short cv16 = f2b16(cv);
      cb[((size_t)(b * 64 + o)) * 4096 + n0 + ns * 16 + l15] = cv16;
      clds[ns * 16 + l15][o] = cv16;
    }
  }
  __syncthreads();

  // ---- QKV: 10 tiles (5 row-tiles x 2 n-subtiles) over 4 waves ----
  #pragma unroll
  for (int i = 0; i < 3; ++i) {
    int tau = w + 4 * i;
    if (tau >= 10) break;
    int t5 = tau % 5, ns = tau / 5;
    int wrow = t5 * 16 + l15;
    f32x4 a2 = zf;
    #pragma unroll
    for (int kk = 0; kk < 2; ++kk) {
      int k = kk * 32 + lg * 8;
      const float* wp = (wrow < 8)  ? (q_w + wrow * 64 + k)
                      : (wrow < 16) ? (k_w + (wrow - 8) * 64 + k)
                                    : (v_w + (wrow - 16) * 64 + k);
      float4 w0 = *(const float4*)wp;
      float4 w1 = *(const float4*)(wp + 4);
      u16x8 pk;
      pk[0] = f2b16(w0.x); pk[1] = f2b16(w0.y);
      pk[2] = f2b16(w0.z); pk[3] = f2b16(w0.w);
      pk[4] = f2b16(w1.x); pk[5] = f2b16(w1.y);
      pk[6] = f2b16(w1.z); pk[7] = f2b16(w1.w);
      bf16x8 bfv = *(const bf16x8*)(&clds[ns * 16 + l15][k]);
      a2 = __builtin_amdgcn_mfma_f32_16x16x32_bf16(
          __builtin_bit_cast(bf16x8, pk), bfv, a2, 0, 0, 0);
    }
    int ngl = n0 + ns * 16 + l15;
    if (t5 == 0) {
      u16x4 pk;
      #pragma unroll
      for (int r = 0; r < 4; ++r) {
        int row = lg * 4 + r;
        float val;
        if (row < 8) val = (a2[r] + q_b[row]) * LOG2E;   // exp2-domain Q
        else         val = a2[r] + k_b[row - 8];
        pk[r] = f2b16(val);
      }
      if (lg < 2)
        *(u16x4*)(Qb + (((size_t)b << 12) + ngl) * 8 + lg * 4) = pk;
      else
        *(u16x4*)(Kb + (((size_t)b << 12) + ngl) * 8 + (lg - 2) * 4) = pk;
    } else {
      #pragma unroll
      for (int r = 0; r < 4; ++r) {
        int vch = (t5 - 1) * 16 + lg * 4 + r;
        vstage[vch][ns * 16 + l15] = f2b16(a2[r] + v_b[vch]);
      }
    }
  }
  __syncthreads();

  // ---- coalesced V store: 64ch x 32n ----
  #pragma unroll
  for (int i = 0; i < 2; ++i) {
    int idx = t + 256 * i;           // 0..511
    int row = idx >> 3, seg = idx & 7;
    u16x4 pv = *(const u16x4*)(&vstage[row][seg * 4]);
    *(u16x4*)(Vb + ((size_t)(b * 64 + row)) * 4096 + n0 + seg * 4) = pv;
  }
}

// ===========================================================================
// attn_partial: flash attention, KV chunk of 512. 2048 blocks.
// Staged K/V with T14 2-phase prefetch: regs loaded for tile t+1 right after
// the post-write barrier; compute on tile t hides the latency.
__global__ __launch_bounds__(256) void attn_partial_kernel(
    const unsigned short* __restrict__ Qb, const unsigned short* __restrict__ Kb,
    const unsigned short* __restrict__ Vb,
    unsigned short* __restrict__ Opart, float* __restrict__ ml)
{
  __shared__ __attribute__((aligned(16))) unsigned short klds[64][8];
  __shared__ __attribute__((aligned(16))) unsigned short vlds[64][72];
  // P in B-fragment layout: [wave][kk][q=l15][idx]; row stride 40 elems = 80B
  __shared__ __attribute__((aligned(16))) unsigned short plds[4][2][16][40];

  const int t = threadIdx.x;
  const int bid = blockIdx.x;
  const int qt = bid & 63;
  const int b = (bid >> 6) & 3;
  const int ci = bid >> 8;            // KV chunk 0..7 (512 each)
  const int n0 = qt << 6;
  const int l = t & 63, w = t >> 6;
  const int l15 = l & 15, lg = l >> 4;

  bf16x8 qf = {0, 0, 0, 0, 0, 0, 0, 0};
  if (lg == 0)
    qf = *(const bf16x8*)(Qb + (((size_t)b << 12) + n0 + w * 16 + l15) * 8);

  f32x4 zf = {0.f, 0.f, 0.f, 0.f};
  f32x4 O[4];                         // O^T: lane ch=ct*16+lg*4+r, q=l15
  O[0] = O[1] = O[2] = O[3] = zf;
  float m_run = -INFINITY;            // per-lane scalars (q = l15)
  float l_run = 0.f;

  // staging geometry (per thread): K only t<64; V two rows
  const int vrow0 = t >> 3, voff0 = t & 7;          // +256 -> row+32
  const unsigned short* Kb_base = Kb + ((size_t)b << 12) * 8;
  const unsigned short* Vb_base = Vb + ((size_t)(b * 64)) * 4096;

  const int m_lo = ci << 9, m_hi = (ci + 1) << 9;

  // ---- prologue: prefetch tile m_lo into registers ----
  int4 kreg{}, vreg0{}, vreg1{};
  if (t < 64)
    kreg = *(const int4*)(Kb_base + (size_t)(m_lo + t) * 8);
  vreg0 = *(const int4*)(Vb_base + (size_t)vrow0 * 4096 + m_lo + voff0 * 8);
  vreg1 = *(const int4*)(Vb_base + (size_t)(vrow0 + 32) * 4096 + m_lo + voff0 * 8);

  for (int m0 = m_lo; m0 < m_hi; m0 += 64) {
    // ---- write staged regs to LDS ----
    if (t < 64) *(int4*)(&klds[t][0]) = kreg;
    *(int4*)(&vlds[vrow0][voff0 * 8]) = vreg0;
    *(int4*)(&vlds[vrow0 + 32][voff0 * 8]) = vreg1;
    __syncthreads();

    // ---- issue next tile's loads (latency hidden under compute below) ----
    if (m0 + 64 < m_hi) {
      if (t < 64)
        kreg = *(const int4*)(Kb_base + (size_t)(m0 + 64 + t) * 8);
      vreg0 = *(const int4*)(Vb_base + (size_t)vrow0 * 4096 + (m0 + 64) + voff0 * 8);
      vreg1 = *(const int4*)(Vb_base + (size_t)(vrow0 + 32) * 4096 + (m0 + 64) + voff0 * 8);
    }

    // ---- energy (swapped): e[mt][r] = E[kv=mt*16+lg*4+r][q=l15] ----
    f32x4 e[4];
    #pragma unroll
    for (int mt = 0; mt < 4; ++mt) {
      bf16x8 kf = *(const bf16x8*)(&klds[mt * 16 + l15][0]);
      e[mt] = __builtin_amdgcn_mfma_f32_16x16x32_bf16(kf, qf, zf, 0, 0, 0);
    }

    // ---- in-register softmax for q = l15 ----
    float vm = fmaxf(fmaxf(fmaxf(e[0][0], e[0][1]), fmaxf(e[0][2], e[0][3])),
                     fmaxf(fmaxf(e[1][0], e[1][1]), fmaxf(e[1][2], e[1][3])));
    float vm2 = fmaxf(fmaxf(fmaxf(e[2][0], e[2][1]), fmaxf(e[2][2], e[2][3])),
                      fmaxf(fmaxf(e[3][0], e[3][1]), fmaxf(e[3][2], e[3][3])));
    vm = fmaxf(vm, vm2);
    vm = fmaxf(vm, __shfl_xor(vm, 16));
    vm = fmaxf(vm, __shfl_xor(vm, 32));

    bool nosk = __any(vm > m_run + 8.f);   // T13: rescale only on real growth
    float nm = nosk ? fmaxf(m_run, vm) : m_run;
    float s = 0.f;
    #pragma unroll
    for (int mt = 0; mt < 4; ++mt) {
      #pragma unroll
      for (int r = 0; r < 4; ++r) {
        float p = __builtin_amdgcn_exp2f(e[mt][r] - nm);
        e[mt][r] = p;
        s += p;
      }
    }
    s += __shfl_xor(s, 16);
    s += __shfl_xor(s, 32);
    if (nosk) {
      float sc = __builtin_amdgcn_exp2f(m_run - nm);
      l_run = l_run * sc + s;
      m_run = nm;
      #pragma unroll
      for (int ct = 0; ct < 4; ++ct)
        #pragma unroll
        for (int r = 0; r < 4; ++r) O[ct][r] *= sc;
    } else {
      l_run += s;
    }

    // ---- write P in B-fragment layout (4x ds_write_b64, per-wave buffer) ----
    #pragma unroll
    for (int mt = 0; mt < 4; ++mt) {
      u16x4 pk;
      #pragma unroll
      for (int r = 0; r < 4; ++r) pk[r] = f2b16(e[mt][r]);
      int kk = mt >> 1;
      int lgr = 2 * (mt & 1) + (lg >> 1);
      int j0 = 4 * (lg & 1);
      *(u16x4*)(&plds[w][kk][l15][lgr * 8 + j0]) = pk;
    }
    // same-wave RAW on plds: in-order DS per wave + compiler lgkmcnt

    // ---- PV (swapped): O^T[ct] += V[ch][kv] . P[kv][q] ----
    #pragma unroll
    for (int ct = 0; ct < 4; ++ct) {
      #pragma unroll
      for (int kk = 0; kk < 2; ++kk) {
        bf16x8 pfr = *(const bf16x8*)(&plds[w][kk][l15][lg * 8]);
        bf16x8 vf = *(const bf16x8*)(&vlds[ct * 16 + l15][kk * 32 + lg * 8]);
        O[ct] = __builtin_amdgcn_mfma_f32_16x16x32_bf16(vf, pfr, O[ct], 0, 0, 0);
      }
    }
    __syncthreads();   // all waves done with klds/vlds before next write
  }

  // ---- store partials: O^T bf16 + (m,l) f32 ----
  const size_t pb = ((size_t)(ci * 4 + b)) << 12;
  const int qg = n0 + w * 16 + l15;
  #pragma unroll
  for (int ct = 0; ct < 4; ++ct) {
    u16x4 pk;
    #pragma unroll
    for (int r = 0; r < 4; ++r) pk[r] = f2b16(O[ct][r]);
    *(u16x4*)(Opart + (pb + qg) * 64 + ct * 16 + lg * 4) = pk;
  }
  if (lg == 0) {
    float2 mv;
    mv.x = m_run; mv.y = l_run;
    *(float2*)(ml + (pb + qg) * 2) = mv;
  }
}

// ===========================================================================
// combine: merge 8 KV-chunk partials + fused epilogue. 1024 blocks, 16 q each.
__global__ __launch_bounds__(256) void combine_kernel(
    const unsigned short* __restrict__ Opart, const float* __restrict__ ml,
    const unsigned short* __restrict__ cb, const float* __restrict__ xin,
    const float* __restrict__ psi_w, const float* __restrict__ psi_b,
    const float* __restrict__ bnp_w, const float* __restrict__ bnp_b,
    const float* __restrict__ bnp_m, const float* __restrict__ bnp_v,
    const float* __restrict__ sa_gamma,
    float* __restrict__ out)
{
  __shared__ __attribute__((aligned(16))) unsigned short c_lds[64][20];
  __shared__ __attribute__((aligned(8))) float2 ml_lds[16][8];
  __shared__ float psi_lds[16];

  const int t = threadIdx.x;
  const int bid = blockIdx.x;
  const int b = bid >> 8;
  const int n0 = (bid & 255) << 4;

  {
    int row = t >> 2, seg = t & 3;
    *(u16x4*)(&c_lds[row][seg * 4]) =
        *(const u16x4*)(cb + ((size_t)(b * 64 + row)) * 4096 + n0 + seg * 4);
  }
  if (t < 128) {
    int q = t >> 3, ci = t & 7;
    ml_lds[q][ci] = *(const float2*)(ml + ((((size_t)(ci * 4 + b)) << 12) + n0 + q) * 2);
  }
  __syncthreads();

  const float invp = bnp_w[0] * rsqrtf(bnp_v[0] + EPSV);
  const float psi_c = (psi_b[0] - bnp_m[0]) * invp + bnp_b[0];
  const float gamma = sa_gamma[0];

  const int q = t >> 4, cg = t & 15;
  const int qg = n0 + q;

  float M = -INFINITY;
  #pragma unroll
  for (int ci = 0; ci < 8; ++ci) M = fmaxf(M, ml_lds[q][ci].x);
  float L = 0.f, wgt[8];
  #pragma unroll
  for (int ci = 0; ci < 8; ++ci) {
    wgt[ci] = __builtin_amdgcn_exp2f(ml_lds[q][ci].x - M);
    L += wgt[ci] * ml_lds[q][ci].y;
  }
  float o4[4] = {0.f, 0.f, 0.f, 0.f};
  #pragma unroll
  for (int ci = 0; ci < 8; ++ci) {
    u16x4 p = *(const u16x4*)(Opart + ((((size_t)(ci * 4 + b)) << 12) + qg) * 64 + cg * 4);
    float wv = wgt[ci];
    #pragma unroll
    for (int k = 0; k < 4; ++k) o4[k] += wv * b2f(p[k]);
  }
  const float invL = 1.f / L;
  float ps = 0.f;
  #pragma unroll
  for (int k = 0; k < 4; ++k) {
    int ch = cg * 4 + k;
    ps += (psi_w[ch] * invp) * (gamma * (o4[k] * invL) + b2f(c_lds[ch][q]));
  }
  ps += __shfl_xor(ps, 1);
  ps += __shfl_xor(ps, 2);
  ps += __shfl_xor(ps, 4);
  ps += __shfl_xor(ps, 8);
  if (cg == 0)
    psi_lds[q] = 1.f / (1.f + __expf(-(ps + psi_c)));
  __syncthreads();

  #pragma unroll
  for (int i = 0; i < 2; ++i) {
    int idx = t + 256 * i;
    int f = idx >> 2, c4 = idx & 3;
    size_t off = ((size_t)(b * 128 + f)) * 4096 + n0 + c4 * 4;
    float4 xv = *(const float4*)(xin + off);
    float4 ov;
    ov.x = xv.x * psi_lds[c4 * 4 + 0];
    ov.y = xv.y * psi_lds[c4 * 4 + 1];
    ov.z = xv.z * psi_lds[c4 * 4 + 2];
    ov.w = xv.w * psi_lds[c4 * 4 + 3];
    *(float4*)(out + off) = ov;
  }
}

// ===========================================================================
extern "C" void kernel_launch(void* const* d_in, const int* in_sizes, int n_in,
                              void* d_out, int out_size, void* d_ws, size_t ws_size,
                              hipStream_t stream) {
  (void)in_sizes; (void)n_in; (void)out_size; (void)ws_size;
  const float* g     = (const float*)d_in[0];
  const float* x     = (const float*)d_in[1];
  const float* wg_w  = (const float*)d_in[2];
  const float* wg_b  = (const float*)d_in[3];
  const float* bng_w = (const float*)d_in[4];
  const float* bng_b = (const float*)d_in[5];
  const float* bng_m = (const float*)d_in[6];
  const float* bng_v = (const float*)d_in[7];
  const float* wx_w  = (const float*)d_in[8];
  const float* wx_b  = (const float*)d_in[9];
  const float* bnx_w = (const float*)d_in[10];
  const float* bnx_b = (const float*)d_in[11];
  const float* bnx_m = (const float*)d_in[12];
  const float* bnx_v = (const float*)d_in[13];
  const float* q_w   = (const float*)d_in[14];
  const float* q_b   = (const float*)d_in[15];
  const float* k_w   = (const float*)d_in[16];
  const float* k_b   = (const float*)d_in[17];
  const float* v_w   = (const float*)d_in[18];
  const float* v_b   = (const float*)d_in[19];
  const float* sa_g  = (const float*)d_in[20];
  const float* psi_w = (const float*)d_in[21];
  const float* psi_b = (const float*)d_in[22];
  const float* bnp_w = (const float*)d_in[23];
  const float* bnp_b = (const float*)d_in[24];
  const float* bnp_m = (const float*)d_in[25];
  const float* bnp_v = (const float*)d_in[26];
  float* out = (float*)d_out;

  char* ws = (char*)d_ws;
  unsigned short* cb = (unsigned short*)(ws + C_OFF);
  unsigned short* Qb = (unsigned short*)(ws + Q_OFF);
  unsigned short* Kb = (unsigned short*)(ws + K_OFF);
  unsigned short* Vb = (unsigned short*)(ws + V_OFF);
  unsigned short* Opart = (unsigned short*)(ws + OPART_OFF);
  float* mlb = (float*)(ws + ML_OFF);

  hipLaunchKernelGGL(conv_fused_kernel, dim3(512), dim3(256), 0, stream,
                     g, x, wg_w, wg_b, bng_w, bng_b, bng_m, bng_v,
                     wx_w, wx_b, bnx_w, bnx_b, bnx_m, bnx_v,
                     q_w, q_b, k_w, k_b, v_w, v_b,
                     cb, Qb, Kb, Vb);

  hipLaunchKernelGGL(attn_partial_kernel, dim3(2048), dim3(256), 0, stream,
                     Qb, Kb, Vb, Opart, mlb);

  hipLaunchKernelGGL(combine_kernel, dim3(1024), dim3(256), 0, stream,
                     Opart, mlb, cb, x,
                     psi_w, psi_b, bnp_w, bnp_b, bnp_m, bnp_v, sa_g,
                     out);
}